// Round 5
// baseline (296.024 us; speedup 1.0000x reference)
//
#include <hip/hip_runtime.h>

// MLP_48687749268221: out[e] = W3 @ relu(W2 @ relu(W1 @ concat(drug[i0],dis[i1]) + b1) + b2) + b3
// E = 2e6, dims 256 -> 128 -> 64 -> 1. bf16 MFMA, f32 accumulate.
// Round 5: 2x2 wave split (edge-half x unit-half) halves per-block LDS read traffic;
// gather writes 1 row per lane (conflict-free phases); W1 streamed 4 frags deep.

typedef __bf16 bf16x8 __attribute__((ext_vector_type(8)));
typedef unsigned short u16x8 __attribute__((ext_vector_type(8)));
typedef float f32x4 __attribute__((ext_vector_type(4)));

static __device__ __forceinline__ unsigned short f2b(float f) {
  // f32 -> bf16 RTNE (inputs finite)
  unsigned int u = __builtin_bit_cast(unsigned int, f);
  u += 0x7FFFu + ((u >> 16) & 1u);
  return (unsigned short)(u >> 16);
}

static __device__ __forceinline__ f32x4 mfma_bf16(u16x8 a, u16x8 b, f32x4 c) {
  return __builtin_amdgcn_mfma_f32_16x16x32_bf16(
      __builtin_bit_cast(bf16x8, a), __builtin_bit_cast(bf16x8, b), c, 0, 0, 0);
}

// ---------- prologue 1: f32 tables -> bf16 tables ----------
__global__ void cvt_tables(const float* __restrict__ a, const float* __restrict__ b,
                           unsigned short* __restrict__ oa, unsigned short* __restrict__ ob,
                           int na, int nb) {
  const int t = blockIdx.x * blockDim.x + threadIdx.x;
  const int ta = na >> 3;
  const float* src;
  unsigned short* dst;
  int i;
  if (t < ta) {
    src = a; dst = oa; i = t;
  } else {
    i = t - ta;
    if (i >= (nb >> 3)) return;
    src = b; dst = ob;
  }
  const float4 f0 = *(const float4*)(src + i * 8);
  const float4 f1 = *(const float4*)(src + i * 8 + 4);
  u16x8 v;
  v[0] = f2b(f0.x); v[1] = f2b(f0.y); v[2] = f2b(f0.z); v[3] = f2b(f0.w);
  v[4] = f2b(f1.x); v[5] = f2b(f1.y); v[6] = f2b(f1.z); v[7] = f2b(f1.w);
  *(u16x8*)(dst + i * 8) = v;
}

// ---------- prologue 2: weights -> bf16 in A-fragment order ----------
// Frag (16x16x32): lane l holds elem[dim][k], dim = 16*t + (l&15), k = 32*kt + 8*(l>>4) + j.
// W1 slot t = (ut*8 + kt)*64 + l  (ut 0..7, kt 0..7); W2: (nt2*4 + kt)*64 + l (nt2 0..3, kt 0..3).
__global__ void cvt_weights(const float* __restrict__ W1, const float* __restrict__ W2,
                            unsigned short* __restrict__ o1, unsigned short* __restrict__ o2) {
  const int t = blockIdx.x * blockDim.x + threadIdx.x;
  if (t < 4096) {
    const int l = t & 63, kt = (t >> 6) & 7, ut = t >> 9;
    const int n = 16 * ut + (l & 15), k0 = 32 * kt + 8 * (l >> 4);
    const float* src = W1 + n * 256 + k0;
    u16x8 v;
#pragma unroll
    for (int j = 0; j < 8; ++j) v[j] = f2b(src[j]);
    *(u16x8*)(o1 + t * 8) = v;
  } else if (t < 5120) {
    const int u = t - 4096;
    const int l = u & 63, kt = (u >> 6) & 3, nt = u >> 8;
    const int n = 16 * nt + (l & 15), k0 = 32 * kt + 8 * (l >> 4);
    const float* src = W2 + n * 128 + k0;
    u16x8 v;
#pragma unroll
    for (int j = 0; j < 8; ++j) v[j] = f2b(src[j]);
    *(u16x8*)(o2 + u * 8) = v;
  }
}

// ---------- main fused kernel ----------
// 256 threads = 4 waves. Wave (wm, wn2): edges [32wm,32wm+32), L1 units [64wn2,64wn2+64),
// L2 units [32wn2,32wn2+32). Tile = 64 edges. LDS: A [64][512 B] swizzled; H1 [64][256 B]
// aliased over A; partials [2][64] f32. ~33.3 KB -> 4 blocks/CU.
__global__ __launch_bounds__(256, 4) void mlp_fused(
    const unsigned short* __restrict__ drugB, const unsigned short* __restrict__ disB,
    const int* __restrict__ eidx, const unsigned short* __restrict__ w1frag,
    const unsigned short* __restrict__ w2frag, const float* __restrict__ b1,
    const float* __restrict__ b2, const float* __restrict__ W3,
    const float* __restrict__ b3, float* __restrict__ out, int E) {
  __shared__ __align__(16) unsigned char smem[32768 + 512];
  unsigned char* Abase = smem;
  float* partials = (float*)(smem + 32768);

  const int tid = threadIdx.x;
  const int wv = tid >> 6;
  const int wm = wv >> 1;    // edge half 0..1
  const int wn2 = wv & 1;    // unit half 0..1
  const int l = tid & 63;
  const int l15 = l & 15;
  const int lq = l >> 4;
  const int e0 = blockIdx.x * 64;

  // ---- gather: wave wv writes byte-quarter [128*wv, +128) of ALL 64 rows; 1 row/lane ----
  {
    const int q = wv;
    int e = e0 + l;
    if (e >= E) e = E - 1;
    const int idx = eidx[(q >> 1) * E + e];  // q<2: drug, q>=2: dis
    const unsigned short* src = ((q < 2) ? drugB : disB) + (long)idx * 128 + (q & 1) * 64;
    unsigned char* rowp = Abase + l * 512;
    const int base = q * 128;
    const int swz = (l & 7) << 4;
#pragma unroll
    for (int c = 0; c < 8; ++c) {
      const u16x8 v = *(const u16x8*)(src + c * 8);
      *(u16x8*)(rowp + ((base + c * 16) ^ swz)) = v;
    }
  }
  __syncthreads();

  // ---- layer 1: D1[unit][edge]; A = W1 frags (streamed 4-wide), B = edge frags from LDS ----
  f32x4 acc1[4][2];
#pragma unroll
  for (int uti = 0; uti < 4; ++uti) {
    acc1[uti][0] = (f32x4){0.f, 0.f, 0.f, 0.f};
    acc1[uti][1] = (f32x4){0.f, 0.f, 0.f, 0.f};
  }
  // wave's W1 band: ut = 4*wn2 + uti; frag (ut, kt) at ((ut*8 + kt)*64 + l)*8 shorts
  const unsigned short* w1p = w1frag + ((4 * wn2) * 512 + l) * 8;
  u16x8 nf[4];
#pragma unroll
  for (int uti = 0; uti < 4; ++uti) nf[uti] = *(const u16x8*)(w1p + uti * 512 * 8);
#pragma unroll
  for (int kt = 0; kt < 8; ++kt) {
    u16x8 cf[4];
#pragma unroll
    for (int uti = 0; uti < 4; ++uti) cf[uti] = nf[uti];
    if (kt < 7) {
#pragma unroll
      for (int uti = 0; uti < 4; ++uti)
        nf[uti] = *(const u16x8*)(w1p + (uti * 512 + (kt + 1) * 64) * 8);
    }
#pragma unroll
    for (int ntl = 0; ntl < 2; ++ntl) {
      const int e = 32 * wm + 16 * ntl + l15;
      const u16x8 b = *(const u16x8*)(Abase + e * 512 + ((64 * kt + 16 * lq) ^ ((e & 7) << 4)));
#pragma unroll
      for (int uti = 0; uti < 4; ++uti) acc1[uti][ntl] = mfma_bf16(cf[uti], b, acc1[uti][ntl]);
    }
  }
  __syncthreads();  // all waves done reading A before H1 overwrites it

  // ---- H1 epilogue: bias+relu, ds_write_b64 of 4 consecutive units ----
  // lane holds D1[16*(4wn2+uti) + 4lq + i][32wm + 16ntl + l15]
#pragma unroll
  for (int uti = 0; uti < 4; ++uti) {
    const float4 bv = *(const float4*)(b1 + 64 * wn2 + 16 * uti + 4 * lq);
#pragma unroll
    for (int ntl = 0; ntl < 2; ++ntl) {
      const int e = 32 * wm + 16 * ntl + l15;
      float h0 = acc1[uti][ntl][0] + bv.x; h0 = h0 > 0.f ? h0 : 0.f;
      float h1 = acc1[uti][ntl][1] + bv.y; h1 = h1 > 0.f ? h1 : 0.f;
      float h2 = acc1[uti][ntl][2] + bv.z; h2 = h2 > 0.f ? h2 : 0.f;
      float h3 = acc1[uti][ntl][3] + bv.w; h3 = h3 > 0.f ? h3 : 0.f;
      ushort4 hv;
      hv.x = f2b(h0); hv.y = f2b(h1); hv.z = f2b(h2); hv.w = f2b(h3);
      *(ushort4*)(Abase + e * 256 +
                  ((32 * (4 * wn2 + uti) + 8 * lq) ^ ((e & 7) << 4))) = hv;
    }
  }

  // ---- W2 frags (8): wave's L2 units [32wn2, +32) -> nt2 = 2wn2 + j ----
  u16x8 w2fr[2][4];
#pragma unroll
  for (int j = 0; j < 2; ++j)
#pragma unroll
    for (int kt = 0; kt < 4; ++kt)
      w2fr[j][kt] = *(const u16x8*)(w2frag + (((2 * wn2 + j) * 4 + kt) * 64 + l) * 8);
  __syncthreads();

  // ---- layer 2: D2[n2][edge]; A = W2 frags, B = H1 frags from LDS ----
  f32x4 acc2[2][2];
#pragma unroll
  for (int j = 0; j < 2; ++j) {
    acc2[j][0] = (f32x4){0.f, 0.f, 0.f, 0.f};
    acc2[j][1] = (f32x4){0.f, 0.f, 0.f, 0.f};
  }
#pragma unroll
  for (int kt = 0; kt < 4; ++kt) {
#pragma unroll
    for (int ntl = 0; ntl < 2; ++ntl) {
      const int e = 32 * wm + 16 * ntl + l15;
      const u16x8 b = *(const u16x8*)(Abase + e * 256 + ((64 * kt + 16 * lq) ^ ((e & 7) << 4)));
#pragma unroll
      for (int j = 0; j < 2; ++j) acc2[j][ntl] = mfma_bf16(w2fr[j][kt], b, acc2[j][ntl]);
    }
  }

  // ---- layer 3: relu(.+b2) dot W3 over the wave's 32-unit band; reduce over lq ----
  const float4 b2v0 = *(const float4*)(b2 + 32 * wn2 + 4 * lq);
  const float4 b2v1 = *(const float4*)(b2 + 32 * wn2 + 16 + 4 * lq);
  const float4 w3v0 = *(const float4*)(W3 + 32 * wn2 + 4 * lq);
  const float4 w3v1 = *(const float4*)(W3 + 32 * wn2 + 16 + 4 * lq);
#pragma unroll
  for (int ntl = 0; ntl < 2; ++ntl) {
    float h, s = 0.f;
    h = acc2[0][ntl][0] + b2v0.x; s += (h > 0.f ? h : 0.f) * w3v0.x;
    h = acc2[0][ntl][1] + b2v0.y; s += (h > 0.f ? h : 0.f) * w3v0.y;
    h = acc2[0][ntl][2] + b2v0.z; s += (h > 0.f ? h : 0.f) * w3v0.z;
    h = acc2[0][ntl][3] + b2v0.w; s += (h > 0.f ? h : 0.f) * w3v0.w;
    h = acc2[1][ntl][0] + b2v1.x; s += (h > 0.f ? h : 0.f) * w3v1.x;
    h = acc2[1][ntl][1] + b2v1.y; s += (h > 0.f ? h : 0.f) * w3v1.y;
    h = acc2[1][ntl][2] + b2v1.z; s += (h > 0.f ? h : 0.f) * w3v1.z;
    h = acc2[1][ntl][3] + b2v1.w; s += (h > 0.f ? h : 0.f) * w3v1.w;
    s += __shfl_xor(s, 16, 64);
    s += __shfl_xor(s, 32, 64);
    if (l < 16) partials[wn2 * 64 + 32 * wm + 16 * ntl + l15] = s;
  }
  __syncthreads();

  if (tid < 64) {
    const int e = e0 + tid;
    if (e < E) out[e] = partials[tid] + partials[64 + tid] + b3[0];
  }
}

extern "C" void kernel_launch(void* const* d_in, const int* in_sizes, int n_in,
                              void* d_out, int out_size, void* d_ws, size_t ws_size,
                              hipStream_t stream) {
  const float* drug = (const float*)d_in[0];
  const float* dis = (const float*)d_in[1];
  const int* eidx = (const int*)d_in[2];
  const float* W1 = (const float*)d_in[3];
  const float* b1 = (const float*)d_in[4];
  const float* W2 = (const float*)d_in[5];
  const float* b2 = (const float*)d_in[6];
  const float* W3 = (const float*)d_in[7];
  const float* b3 = (const float*)d_in[8];
  float* out = (float*)d_out;

  const int na = in_sizes[0];           // 10000*128
  const int nb = in_sizes[1];           // 5000*128
  const int E = in_sizes[2] / 2;        // 2e6

  unsigned short* ws = (unsigned short*)d_ws;
  unsigned short* drugB = ws;
  unsigned short* disB = ws + na;
  unsigned short* w1f = ws + na + nb;
  unsigned short* w2f = w1f + 128 * 256;
  // total ws use: (na+nb)*2 + 81920 bytes ~= 3.92 MB

  const int tct = (na + nb) >> 3;
  cvt_tables<<<(tct + 255) / 256, 256, 0, stream>>>(drug, dis, drugB, disB, na, nb);
  cvt_weights<<<20, 256, 0, stream>>>(W1, W2, w1f, w2f);

  const int grid = (E + 63) / 64;
  mlp_fused<<<grid, 256, 0, stream>>>(drugB, disB, eidx, w1f, w2f, b1, b2, W3, b3, out, E);
}

// Round 6
// 226.661 us; speedup vs baseline: 1.3060x; 1.3060x over previous
//
#include <hip/hip_runtime.h>

// MLP_48687749268221: out[e] = W3 @ relu(W2 @ relu(W1 @ concat(drug[i0],dis[i1]) + b1) + b2) + b3
// E = 2e6, dims 256 -> 128 -> 64 -> 1. bf16 MFMA, f32 accumulate.
// Round 6: round-4 (4,1) wave split (wave = all 64 edges x 32 units, W1 64KB/block)
// + round-5 conflict-free gather (1 row/lane) + 2-deep W1 prefetch.

typedef __bf16 bf16x8 __attribute__((ext_vector_type(8)));
typedef unsigned short u16x8 __attribute__((ext_vector_type(8)));
typedef float f32x4 __attribute__((ext_vector_type(4)));

static __device__ __forceinline__ unsigned short f2b(float f) {
  // f32 -> bf16 RTNE (inputs finite)
  unsigned int u = __builtin_bit_cast(unsigned int, f);
  u += 0x7FFFu + ((u >> 16) & 1u);
  return (unsigned short)(u >> 16);
}

static __device__ __forceinline__ f32x4 mfma_bf16(u16x8 a, u16x8 b, f32x4 c) {
  return __builtin_amdgcn_mfma_f32_16x16x32_bf16(
      __builtin_bit_cast(bf16x8, a), __builtin_bit_cast(bf16x8, b), c, 0, 0, 0);
}

// ---------- prologue 1: f32 tables -> bf16 tables ----------
__global__ void cvt_tables(const float* __restrict__ a, const float* __restrict__ b,
                           unsigned short* __restrict__ oa, unsigned short* __restrict__ ob,
                           int na, int nb) {
  const int t = blockIdx.x * blockDim.x + threadIdx.x;
  const int ta = na >> 3;
  const float* src;
  unsigned short* dst;
  int i;
  if (t < ta) {
    src = a; dst = oa; i = t;
  } else {
    i = t - ta;
    if (i >= (nb >> 3)) return;
    src = b; dst = ob;
  }
  const float4 f0 = *(const float4*)(src + i * 8);
  const float4 f1 = *(const float4*)(src + i * 8 + 4);
  u16x8 v;
  v[0] = f2b(f0.x); v[1] = f2b(f0.y); v[2] = f2b(f0.z); v[3] = f2b(f0.w);
  v[4] = f2b(f1.x); v[5] = f2b(f1.y); v[6] = f2b(f1.z); v[7] = f2b(f1.w);
  *(u16x8*)(dst + i * 8) = v;
}

// ---------- prologue 2: weights -> bf16 in A-fragment order ----------
// Frag (16x16x32): lane l holds elem[dim][k], dim = 16*t + (l&15), k = 32*kt + 8*(l>>4) + j.
// W1 slot t = (ut*8 + kt)*64 + l  (ut 0..7, kt 0..7); W2: (nt2*4 + kt)*64 + l (nt2 0..3, kt 0..3).
__global__ void cvt_weights(const float* __restrict__ W1, const float* __restrict__ W2,
                            unsigned short* __restrict__ o1, unsigned short* __restrict__ o2) {
  const int t = blockIdx.x * blockDim.x + threadIdx.x;
  if (t < 4096) {
    const int l = t & 63, kt = (t >> 6) & 7, ut = t >> 9;
    const int n = 16 * ut + (l & 15), k0 = 32 * kt + 8 * (l >> 4);
    const float* src = W1 + n * 256 + k0;
    u16x8 v;
#pragma unroll
    for (int j = 0; j < 8; ++j) v[j] = f2b(src[j]);
    *(u16x8*)(o1 + t * 8) = v;
  } else if (t < 5120) {
    const int u = t - 4096;
    const int l = u & 63, kt = (u >> 6) & 3, nt = u >> 8;
    const int n = 16 * nt + (l & 15), k0 = 32 * kt + 8 * (l >> 4);
    const float* src = W2 + n * 128 + k0;
    u16x8 v;
#pragma unroll
    for (int j = 0; j < 8; ++j) v[j] = f2b(src[j]);
    *(u16x8*)(o2 + u * 8) = v;
  }
}

// ---------- main fused kernel ----------
// 256 threads = 4 waves; wave wn owns W1 units [32wn,32wn+32) and W2 units [16wn,16wn+16),
// sweeps all 64 edges. Tile = 64 edges. LDS: A [64][512 B] swizzled; H1 [64][256 B] aliased
// over A; partials [4][64] f32. ~33.8 KB -> 4 blocks/CU.
__global__ __launch_bounds__(256, 4) void mlp_fused(
    const unsigned short* __restrict__ drugB, const unsigned short* __restrict__ disB,
    const int* __restrict__ eidx, const unsigned short* __restrict__ w1frag,
    const unsigned short* __restrict__ w2frag, const float* __restrict__ b1,
    const float* __restrict__ b2, const float* __restrict__ W3,
    const float* __restrict__ b3, float* __restrict__ out, int E) {
  __shared__ __align__(16) unsigned char smem[32768 + 1024];
  unsigned char* Abase = smem;
  float* partials = (float*)(smem + 32768);

  const int tid = threadIdx.x;
  const int wn = tid >> 6;   // wave 0..3: unit-column quarter (and gather byte-quarter)
  const int l = tid & 63;
  const int l15 = l & 15;
  const int lq = l >> 4;
  const int e0 = blockIdx.x * 64;

  // ---- gather: wave wn writes byte-quarter [128*wn, +128) of ALL 64 rows; 1 row/lane ----
  // Each 16-lane phase touches 16 distinct rows -> swizzle spreads perfectly (2 lanes/slot).
  {
    const int q = wn;
    int e = e0 + l;
    if (e >= E) e = E - 1;
    const int idx = eidx[(q >> 1) * E + e];  // q<2: drug, q>=2: dis
    const unsigned short* src = ((q < 2) ? drugB : disB) + (long)idx * 128 + (q & 1) * 64;
    unsigned char* rowp = Abase + l * 512;
    const int base = q * 128;
    const int swz = (l & 7) << 4;
#pragma unroll
    for (int c = 0; c < 8; ++c) {
      const u16x8 v = *(const u16x8*)(src + c * 8);
      *(u16x8*)(rowp + ((base + c * 16) ^ swz)) = v;
    }
  }

  // ---- W2 A-frags resident, bias/W3 float4 per lane ----
  u16x8 w2f[4];
#pragma unroll
  for (int kt = 0; kt < 4; ++kt)
    w2f[kt] = *(const u16x8*)(w2frag + ((wn * 4 + kt) * 64 + l) * 8);
  const float4 b1v0 = *(const float4*)(b1 + 32 * wn + 4 * lq);
  const float4 b1v1 = *(const float4*)(b1 + 32 * wn + 16 + 4 * lq);
  const float4 b2v = *(const float4*)(b2 + 16 * wn + 4 * lq);
  const float4 w3v = *(const float4*)(W3 + 16 * wn + 4 * lq);
  __syncthreads();

  // ---- layer 1: D1[unit][edge]; A = W1 frags (2-deep prefetch), B = edge frags from LDS ----
  f32x4 acc1[2][4];
#pragma unroll
  for (int uti = 0; uti < 2; ++uti)
#pragma unroll
    for (int nt = 0; nt < 4; ++nt) acc1[uti][nt] = (f32x4){0.f, 0.f, 0.f, 0.f};

  // wave's W1 band: ut = 2wn + uti; frag (uti, kt) at w1p + (uti*512 + kt*64)*8 shorts
  const unsigned short* w1p = w1frag + ((2 * wn) * 512 + l) * 8;
  u16x8 nf[2][2];  // [kt parity][uti] -- kt is compile-time under full unroll
  nf[0][0] = *(const u16x8*)(w1p);
  nf[0][1] = *(const u16x8*)(w1p + 512 * 8);
  nf[1][0] = *(const u16x8*)(w1p + 64 * 8);
  nf[1][1] = *(const u16x8*)(w1p + (512 + 64) * 8);
#pragma unroll
  for (int kt = 0; kt < 8; ++kt) {
    const u16x8 c0 = nf[kt & 1][0], c1 = nf[kt & 1][1];
    if (kt < 6) {
      nf[kt & 1][0] = *(const u16x8*)(w1p + ((kt + 2) * 64) * 8);
      nf[kt & 1][1] = *(const u16x8*)(w1p + ((512 + (kt + 2) * 64)) * 8);
    }
#pragma unroll
    for (int nt = 0; nt < 4; ++nt) {
      const int e = 16 * nt + l15;
      const u16x8 b = *(const u16x8*)(Abase + e * 512 + ((64 * kt + 16 * lq) ^ ((e & 7) << 4)));
      acc1[0][nt] = mfma_bf16(c0, b, acc1[0][nt]);
      acc1[1][nt] = mfma_bf16(c1, b, acc1[1][nt]);
    }
  }
  __syncthreads();  // all waves done reading A before H1 overwrites it

  // ---- H1 epilogue: bias+relu, pack 4 bf16 (consecutive units) -> ds_write_b64 ----
  // lane holds D1[32wn + 16uti + 4lq + i][16nt + l15]
#pragma unroll
  for (int uti = 0; uti < 2; ++uti) {
    const float4 bv = uti ? b1v1 : b1v0;
#pragma unroll
    for (int nt = 0; nt < 4; ++nt) {
      const int e = 16 * nt + l15;
      float h0 = acc1[uti][nt][0] + bv.x; h0 = h0 > 0.f ? h0 : 0.f;
      float h1 = acc1[uti][nt][1] + bv.y; h1 = h1 > 0.f ? h1 : 0.f;
      float h2 = acc1[uti][nt][2] + bv.z; h2 = h2 > 0.f ? h2 : 0.f;
      float h3 = acc1[uti][nt][3] + bv.w; h3 = h3 > 0.f ? h3 : 0.f;
      ushort4 hv;
      hv.x = f2b(h0); hv.y = f2b(h1); hv.z = f2b(h2); hv.w = f2b(h3);
      *(ushort4*)(Abase + e * 256 + ((64 * wn + 32 * uti + 8 * lq) ^ ((e & 7) << 4))) = hv;
    }
  }
  __syncthreads();

  // ---- layer 2: D2[n2][edge]; A = W2 frags, B = H1 frags from LDS ----
  f32x4 acc2[4];
#pragma unroll
  for (int nt = 0; nt < 4; ++nt) acc2[nt] = (f32x4){0.f, 0.f, 0.f, 0.f};
#pragma unroll
  for (int kt = 0; kt < 4; ++kt) {
#pragma unroll
    for (int nt = 0; nt < 4; ++nt) {
      const int e = 16 * nt + l15;
      const u16x8 b = *(const u16x8*)(Abase + e * 256 + ((64 * kt + 16 * lq) ^ ((e & 7) << 4)));
      acc2[nt] = mfma_bf16(w2f[kt], b, acc2[nt]);
    }
  }

  // ---- layer 3: relu(.+b2) dot W3 (4 units per lane), reduce over lq with 2 shuffles ----
#pragma unroll
  for (int nt = 0; nt < 4; ++nt) {
    float h0 = acc2[nt][0] + b2v.x; h0 = h0 > 0.f ? h0 : 0.f;
    float h1 = acc2[nt][1] + b2v.y; h1 = h1 > 0.f ? h1 : 0.f;
    float h2 = acc2[nt][2] + b2v.z; h2 = h2 > 0.f ? h2 : 0.f;
    float h3 = acc2[nt][3] + b2v.w; h3 = h3 > 0.f ? h3 : 0.f;
    float s = h0 * w3v.x + h1 * w3v.y + h2 * w3v.z + h3 * w3v.w;
    s += __shfl_xor(s, 16, 64);
    s += __shfl_xor(s, 32, 64);
    if (l < 16) partials[wn * 64 + 16 * nt + l15] = s;
  }
  __syncthreads();

  if (tid < 64) {
    const int e = e0 + tid;
    if (e < E) {
      out[e] = partials[tid] + partials[64 + tid] + partials[128 + tid] +
               partials[192 + tid] + b3[0];
    }
  }
}

extern "C" void kernel_launch(void* const* d_in, const int* in_sizes, int n_in,
                              void* d_out, int out_size, void* d_ws, size_t ws_size,
                              hipStream_t stream) {
  const float* drug = (const float*)d_in[0];
  const float* dis = (const float*)d_in[1];
  const int* eidx = (const int*)d_in[2];
  const float* W1 = (const float*)d_in[3];
  const float* b1 = (const float*)d_in[4];
  const float* W2 = (const float*)d_in[5];
  const float* b2 = (const float*)d_in[6];
  const float* W3 = (const float*)d_in[7];
  const float* b3 = (const float*)d_in[8];
  float* out = (float*)d_out;

  const int na = in_sizes[0];           // 10000*128
  const int nb = in_sizes[1];           // 5000*128
  const int E = in_sizes[2] / 2;        // 2e6

  unsigned short* ws = (unsigned short*)d_ws;
  unsigned short* drugB = ws;
  unsigned short* disB = ws + na;
  unsigned short* w1f = ws + na + nb;
  unsigned short* w2f = w1f + 128 * 256;
  // total ws use: (na+nb)*2 + 81920 bytes ~= 3.92 MB

  const int tct = (na + nb) >> 3;
  cvt_tables<<<(tct + 255) / 256, 256, 0, stream>>>(drug, dis, drugB, disB, na, nb);
  cvt_weights<<<20, 256, 0, stream>>>(W1, W2, w1f, w2f);

  const int grid = (E + 63) / 64;
  mlp_fused<<<grid, 256, 0, stream>>>(drugB, disB, eidx, w1f, w2f, b1, b2, W3, b3, out, E);
}